// Round 1
// baseline (115.649 us; speedup 1.0000x reference)
//
#include <hip/hip_runtime.h>
#include <hip/hip_bf16.h>

typedef __bf16 bf16x8 __attribute__((ext_vector_type(8)));
typedef float  f32x4  __attribute__((ext_vector_type(4)));

static constexpr int D     = 128;
static constexpr int BATCH = 4096;
static constexpr int TILE  = 128;
static constexpr int NT    = BATCH / TILE;     // 32 tiles per dim
static constexpr int TRI   = NT * (NT + 1) / 2; // 528 lower-tri tiles

// ---------------- norms ----------------
__global__ __launch_bounds__(256) void norms_kernel(const float* __restrict__ f,
                                                    float* __restrict__ norms) {
    const int w = threadIdx.x >> 6, lane = threadIdx.x & 63;
    const int row = blockIdx.x * 4 + w;
    const float2 v = *(const float2*)(f + row * D + lane * 2);
    float s = v.x * v.x + v.y * v.y;
    #pragma unroll
    for (int m = 1; m <= 32; m <<= 1) s += __shfl_xor(s, m);
    if (lane == 0) norms[row] = s;
}

// ---------------- fused sim-tile kernel ----------------
// grid: [0, TRI)        -> aa lower-tri tiles (symmetric)
//       [TRI, 2*TRI)    -> bb lower-tri tiles (symmetric)
//       [2*TRI, +1024)  -> ab full tiles
__global__ __launch_bounds__(256) void sim_kernel(const float* __restrict__ feat,
                                                  const float* __restrict__ norms,
                                                  float* __restrict__ rsumA,
                                                  float* __restrict__ rsumB,
                                                  float* __restrict__ abRow,
                                                  float* __restrict__ abCol,
                                                  float* __restrict__ diag) {
    int id = blockIdx.x;
    bool sym;
    int ti, tj;
    const float *FA, *FB, *nA, *nB;
    float *rowAcc, *colAcc;
    if (id < 2 * TRI) {
        sym = true;
        const int base = (id < TRI) ? 0 : BATCH;
        if (id >= TRI) id -= TRI;
        ti = (int)((sqrtf(8.f * (float)id + 1.f) - 1.f) * 0.5f);
        while ((ti + 1) * (ti + 2) / 2 <= id) ++ti;
        while (ti * (ti + 1) / 2 > id) --ti;
        tj = id - ti * (ti + 1) / 2;
        FA = FB = feat + (size_t)base * D;
        nA = nB = norms + base;
        rowAcc = colAcc = (base == 0) ? rsumA : rsumB;
    } else {
        sym = false;
        id -= 2 * TRI;
        ti = id >> 5;
        tj = id & 31;
        FA = feat;           FB = feat + (size_t)BATCH * D;
        nA = norms;          nB = norms + BATCH;
        rowAcc = abRow;      colAcc = abCol;
    }

    // LDS tiles: 128 rows x 128 bf16 (256 B/row), XOR-swizzled in 16B chunks.
    __shared__ __align__(16) unsigned char AsB[TILE * 256];
    __shared__ __align__(16) unsigned char BsB[TILE * 256];

    const int tid = threadIdx.x;
    const float* srcA = FA + (size_t)ti * TILE * D;
    const float* srcB = FB + (size_t)tj * TILE * D;

    // Stage: fp32 global -> bf16 LDS with convert, swizzle byte^=((row&7)<<4).
    for (int c = tid; c < 2048; c += 256) {
        const int row = c >> 4, cin = c & 15;
        const int dst = row * 256 + ((cin ^ (row & 7)) << 4);
        {
            const float4 f0 = *(const float4*)(srcA + row * D + cin * 8);
            const float4 f1 = *(const float4*)(srcA + row * D + cin * 8 + 4);
            union { __bf16 h[8]; float4 v; } pk;
            pk.h[0] = (__bf16)f0.x; pk.h[1] = (__bf16)f0.y;
            pk.h[2] = (__bf16)f0.z; pk.h[3] = (__bf16)f0.w;
            pk.h[4] = (__bf16)f1.x; pk.h[5] = (__bf16)f1.y;
            pk.h[6] = (__bf16)f1.z; pk.h[7] = (__bf16)f1.w;
            *(float4*)(AsB + dst) = pk.v;
        }
        {
            const float4 f0 = *(const float4*)(srcB + row * D + cin * 8);
            const float4 f1 = *(const float4*)(srcB + row * D + cin * 8 + 4);
            union { __bf16 h[8]; float4 v; } pk;
            pk.h[0] = (__bf16)f0.x; pk.h[1] = (__bf16)f0.y;
            pk.h[2] = (__bf16)f0.z; pk.h[3] = (__bf16)f0.w;
            pk.h[4] = (__bf16)f1.x; pk.h[5] = (__bf16)f1.y;
            pk.h[6] = (__bf16)f1.z; pk.h[7] = (__bf16)f1.w;
            *(float4*)(BsB + dst) = pk.v;
        }
    }
    __syncthreads();

    const int lane = tid & 63, w = tid >> 6;
    const int lr = lane & 15, hk = lane >> 4;
    const int qr = (w >> 1) * 64, qc = (w & 1) * 64; // per-wave 64x64 quadrant

    f32x4 acc[4][4];
    #pragma unroll
    for (int i = 0; i < 4; ++i)
        #pragma unroll
        for (int j = 0; j < 4; ++j)
            acc[i][j] = (f32x4){0.f, 0.f, 0.f, 0.f};

    #pragma unroll
    for (int ks = 0; ks < 4; ++ks) {
        bf16x8 av[4], bv[4];
        #pragma unroll
        for (int fi = 0; fi < 4; ++fi) {
            const int row = qr + fi * 16 + lr;
            av[fi] = *(const bf16x8*)(AsB + row * 256 + (((ks * 4 + hk) ^ (row & 7)) << 4));
        }
        #pragma unroll
        for (int fj = 0; fj < 4; ++fj) {
            const int row = qc + fj * 16 + lr;
            bv[fj] = *(const bf16x8*)(BsB + row * 256 + (((ks * 4 + hk) ^ (row & 7)) << 4));
        }
        #pragma unroll
        for (int fi = 0; fi < 4; ++fi)
            #pragma unroll
            for (int fj = 0; fj < 4; ++fj)
                acc[fi][fj] = __builtin_amdgcn_mfma_f32_16x16x32_bf16(av[fi], bv[fj], acc[fi][fj], 0, 0, 0);
    }

    // norms for this wave's rows/cols
    float rowN[4][4], colN[4];
    #pragma unroll
    for (int fi = 0; fi < 4; ++fi)
        #pragma unroll
        for (int r = 0; r < 4; ++r)
            rowN[fi][r] = nA[ti * TILE + qr + fi * 16 + hk * 4 + r];
    #pragma unroll
    for (int fj = 0; fj < 4; ++fj)
        colN[fj] = nB[tj * TILE + qc + fj * 16 + lr];

    // dot -> cauchy sim in-register; handle diagonal
    #pragma unroll
    for (int fi = 0; fi < 4; ++fi) {
        #pragma unroll
        for (int fj = 0; fj < 4; ++fj) {
            #pragma unroll
            for (int r = 0; r < 4; ++r) {
                const float dotv = acc[fi][fj][r];
                float sq = rowN[fi][r] + colN[fj] - 2.f * dotv;
                sq = fmaxf(sq, 0.f);
                float sim = 1.f / (sq + 1.f);
                const int grow = ti * TILE + qr + fi * 16 + hk * 4 + r;
                const int gcol = tj * TILE + qc + fj * 16 + lr;
                if (sym) {
                    if (grow == gcol) sim = 0.f;  // self-mask on aa/bb
                } else {
                    if (grow == gcol) diag[grow] = sim;  // alignment term
                }
                acc[fi][fj][r] = sim;
            }
        }
    }

    // row sums: sum over fj + 16-lane shuffle reduce
    #pragma unroll
    for (int fi = 0; fi < 4; ++fi) {
        float rs[4];
        #pragma unroll
        for (int r = 0; r < 4; ++r)
            rs[r] = acc[fi][0][r] + acc[fi][1][r] + acc[fi][2][r] + acc[fi][3][r];
        #pragma unroll
        for (int r = 0; r < 4; ++r) {
            rs[r] += __shfl_xor(rs[r], 1);
            rs[r] += __shfl_xor(rs[r], 2);
            rs[r] += __shfl_xor(rs[r], 4);
            rs[r] += __shfl_xor(rs[r], 8);
        }
        if (lr == 0) {
            #pragma unroll
            for (int r = 0; r < 4; ++r)
                atomicAdd(&rowAcc[ti * TILE + qr + fi * 16 + hk * 4 + r], rs[r]);
        }
    }

    // col sums: sum over fi,r + cross-quarter shuffle reduce
    // (for sym tiles, off-diagonal tile's colsum is the mirrored row's rowsum)
    const bool doCol = (!sym) || (ti != tj);
    if (doCol) {
        #pragma unroll
        for (int fj = 0; fj < 4; ++fj) {
            float cs = 0.f;
            #pragma unroll
            for (int fi = 0; fi < 4; ++fi)
                #pragma unroll
                for (int r = 0; r < 4; ++r)
                    cs += acc[fi][fj][r];
            cs += __shfl_xor(cs, 16);
            cs += __shfl_xor(cs, 32);
            if (hk == 0)
                atomicAdd(&colAcc[tj * TILE + qc + fj * 16 + lr], cs);
        }
    }
}

// ---------------- final scalar reduce ----------------
__global__ __launch_bounds__(256) void finalize_kernel(const float* __restrict__ rsumA,
                                                       const float* __restrict__ rsumB,
                                                       const float* __restrict__ abRow,
                                                       const float* __restrict__ abCol,
                                                       const float* __restrict__ diag,
                                                       float* __restrict__ out) {
    double s = 0.0;
    for (int i = threadIdx.x; i < BATCH; i += 256) {
        s += -(double)logf(diag[i])
           + 0.5 * (double)logf(abCol[i] + rsumB[i])
           + 0.5 * (double)logf(rsumA[i] + abRow[i]);
    }
    #pragma unroll
    for (int m = 1; m <= 32; m <<= 1) s += __shfl_xor(s, m);
    __shared__ double sh[4];
    const int lane = threadIdx.x & 63, w = threadIdx.x >> 6;
    if (lane == 0) sh[w] = s;
    __syncthreads();
    if (threadIdx.x == 0)
        out[0] = (float)((sh[0] + sh[1] + sh[2] + sh[3]) / (double)BATCH);
}

extern "C" void kernel_launch(void* const* d_in, const int* in_sizes, int n_in,
                              void* d_out, int out_size, void* d_ws, size_t ws_size,
                              hipStream_t stream) {
    const float* feat = (const float*)d_in[0];
    char* ws = (char*)d_ws;
    // ws layout (bytes):
    //   0      : norms  float[8192]   (32 KB)
    //   32768  : rsumA  float[4096]
    //   49152  : rsumB  float[4096]
    //   65536  : abRow  float[4096]
    //   81920  : abCol  float[4096]
    //   98304  : diag   float[4096]
    float* norms = (float*)ws;
    float* rsumA = (float*)(ws + 32768);
    float* rsumB = (float*)(ws + 49152);
    float* abRow = (float*)(ws + 65536);
    float* abCol = (float*)(ws + 81920);
    float* diag  = (float*)(ws + 98304);
    float* out   = (float*)d_out;

    hipMemsetAsync(ws + 32768, 0, 4 * 4096 * sizeof(float), stream);
    norms_kernel<<<8192 / 4, 256, 0, stream>>>(feat, norms);
    const int nblocks = 2 * TRI + NT * NT; // 528 + 528 + 1024 = 2080
    sim_kernel<<<nblocks, 256, 0, stream>>>(feat, norms, rsumA, rsumB, abRow, abCol, diag);
    finalize_kernel<<<1, 256, 0, stream>>>(rsumA, rsumB, abRow, abCol, diag, out);
}

// Round 2
// 108.091 us; speedup vs baseline: 1.0699x; 1.0699x over previous
//
#include <hip/hip_runtime.h>
#include <hip/hip_bf16.h>

typedef __bf16 bf16x8 __attribute__((ext_vector_type(8)));
typedef float  f32x4  __attribute__((ext_vector_type(4)));

static constexpr int D      = 128;
static constexpr int BATCH  = 4096;   // per-half batch
static constexpr int N      = 8192;   // total rows (unified Gram view)
static constexpr int BT     = 256;    // super-tile
static constexpr int NT     = N / BT; // 32
static constexpr int TRI    = NT * (NT + 1) / 2; // 528 lower-tri blocks

__device__ __forceinline__ void load_lds16(const void* g, void* l) {
    __builtin_amdgcn_global_load_lds(
        (const __attribute__((address_space(1))) unsigned int*)g,
        (__attribute__((address_space(3))) unsigned int*)l, 16, 0, 0);
}

// ---------------- prep: fp32 -> bf16 copy + row norms ----------------
__global__ __launch_bounds__(256) void prep_kernel(const float* __restrict__ f,
                                                   unsigned short* __restrict__ fb,
                                                   float* __restrict__ norms) {
    const int w = threadIdx.x >> 6, lane = threadIdx.x & 63;
    const int row = blockIdx.x * 4 + w;
    const float2 v = *(const float2*)(f + (size_t)row * D + lane * 2);
    union { __bf16 h[2]; unsigned int u; } pk;
    pk.h[0] = (__bf16)v.x; pk.h[1] = (__bf16)v.y;
    *(unsigned int*)(fb + (size_t)row * D + lane * 2) = pk.u;
    float s = v.x * v.x + v.y * v.y;
    #pragma unroll
    for (int m = 1; m <= 32; m <<= 1) s += __shfl_xor(s, m);
    if (lane == 0) norms[row] = s;
}

// ---------------- fused 256x256 Gram-tile kernel (lower triangle) ----------------
// Unified view: G[i,j] = cauchy_sim(f_i, f_j), i,j in [0,8192).
// S[i] += row-sum (diag blocks: self-sim zeroed); off-diag blocks also add col sums.
// Stripe blocks (ti == tj+16) hold sim_ab diag: G[4096+k, k] -> diag[k].
__global__ __launch_bounds__(512) void sim_kernel(const unsigned short* __restrict__ fbf,
                                                  const float* __restrict__ norms,
                                                  float* __restrict__ S,
                                                  float* __restrict__ diag) {
    int id = blockIdx.x;
    int ti = (int)((sqrtf(8.f * (float)id + 1.f) - 1.f) * 0.5f);
    while ((ti + 1) * (ti + 2) / 2 <= id) ++ti;
    while (ti * (ti + 1) / 2 > id) --ti;
    const int tj = id - ti * (ti + 1) / 2;
    const bool diagblk = (ti == tj);

    // LDS: two 256-row x 64-bf16 (128B/row) K-half tiles, 32KB each.
    __shared__ __align__(16) unsigned char AsB[BT * 128];
    __shared__ __align__(16) unsigned char BsB[BT * 128];

    const int tid = threadIdx.x;
    const int wv = tid >> 6, lane = tid & 63;
    const int lr = lane & 15, hk = lane >> 4;
    const int qr = (wv >> 2) * 128;   // wave row region (2 x 128)
    const int qc = (wv & 3) * 64;     // wave col region (4 x 64)

    const unsigned char* Abase = (const unsigned char*)fbf + (size_t)ti * BT * 256; // 256B/row
    const unsigned char* Bbase = (const unsigned char*)fbf + (size_t)tj * BT * 256;
    const unsigned char* Brd = diagblk ? AsB : BsB;

    f32x4 acc[8][4];
    #pragma unroll
    for (int i = 0; i < 8; ++i)
        #pragma unroll
        for (int j = 0; j < 4; ++j)
            acc[i][j] = (f32x4){0.f, 0.f, 0.f, 0.f};

    #pragma unroll
    for (int kp = 0; kp < 2; ++kp) {
        if (kp) __syncthreads();   // protect LDS reuse
        // Stage K-half kp: linear LDS dst (wave base + lane*16), pre-swizzled global src.
        #pragma unroll
        for (int it = 0; it < 4; ++it) {
            const int cid = it * 512 + tid;
            const int row = cid >> 3, p = cid & 7;
            const int sw = ((p ^ (row & 7)) << 4);
            load_lds16(Abase + (size_t)row * 256 + kp * 128 + sw,
                       AsB + it * 8192 + wv * 1024);
        }
        if (!diagblk) {
            #pragma unroll
            for (int it = 0; it < 4; ++it) {
                const int cid = it * 512 + tid;
                const int row = cid >> 3, p = cid & 7;
                const int sw = ((p ^ (row & 7)) << 4);
                load_lds16(Bbase + (size_t)row * 256 + kp * 128 + sw,
                           BsB + it * 8192 + wv * 1024);
            }
        }
        __syncthreads();

        #pragma unroll
        for (int l = 0; l < 2; ++l) {
            const int c = l * 4 + hk;
            bf16x8 av[8], bv[4];
            #pragma unroll
            for (int fi = 0; fi < 8; ++fi) {
                const int row = qr + fi * 16 + lr;
                av[fi] = *(const bf16x8*)(AsB + row * 128 + ((c ^ (row & 7)) << 4));
            }
            #pragma unroll
            for (int fj = 0; fj < 4; ++fj) {
                const int row = qc + fj * 16 + lr;
                bv[fj] = *(const bf16x8*)(Brd + row * 128 + ((c ^ (row & 7)) << 4));
            }
            #pragma unroll
            for (int fi = 0; fi < 8; ++fi)
                #pragma unroll
                for (int fj = 0; fj < 4; ++fj)
                    acc[fi][fj] = __builtin_amdgcn_mfma_f32_16x16x32_bf16(av[fi], bv[fj], acc[fi][fj], 0, 0, 0);
        }
    }

    // ---- epilogue: dot -> cauchy sim, diag handling, row/col sums ----
    float colN[4];
    #pragma unroll
    for (int fj = 0; fj < 4; ++fj)
        colN[fj] = norms[tj * BT + qc + fj * 16 + lr];

    const int rowBase = ti * BT;
    const int colBase = tj * BT;
    const bool stripe = (ti == tj + 16);

    #pragma unroll
    for (int fi = 0; fi < 8; ++fi) {
        const int irow = qr + fi * 16 + hk * 4;  // +r
        float rowN[4];
        #pragma unroll
        for (int r = 0; r < 4; ++r)
            rowN[r] = norms[rowBase + irow + r];
        #pragma unroll
        for (int fj = 0; fj < 4; ++fj) {
            const int icol = qc + fj * 16 + lr;
            #pragma unroll
            for (int r = 0; r < 4; ++r) {
                float sq = rowN[r] + colN[fj] - 2.f * acc[fi][fj][r];
                sq = fmaxf(sq, 0.f);
                float sim = __builtin_amdgcn_rcpf(sq + 1.f);
                if (diagblk && (irow + r == icol)) sim = 0.f;       // self-mask
                if (stripe && (irow + r == icol)) diag[colBase + icol] = sim; // ab diag
                acc[fi][fj][r] = sim;
            }
        }
    }

    // row sums: sum over fj, then 16-lane (lr) tree; lr==0 lanes own rows hk*4+r
    #pragma unroll
    for (int fi = 0; fi < 8; ++fi) {
        float rs[4];
        #pragma unroll
        for (int r = 0; r < 4; ++r)
            rs[r] = acc[fi][0][r] + acc[fi][1][r] + acc[fi][2][r] + acc[fi][3][r];
        #pragma unroll
        for (int r = 0; r < 4; ++r) {
            rs[r] += __shfl_xor(rs[r], 1);
            rs[r] += __shfl_xor(rs[r], 2);
            rs[r] += __shfl_xor(rs[r], 4);
            rs[r] += __shfl_xor(rs[r], 8);
        }
        if (lr == 0) {
            #pragma unroll
            for (int r = 0; r < 4; ++r)
                atomicAdd(&S[rowBase + qr + fi * 16 + hk * 4 + r], rs[r]);
        }
    }

    // col sums (off-diagonal blocks only): sum over fi,r then cross-group (hk) tree
    if (!diagblk) {
        #pragma unroll
        for (int fj = 0; fj < 4; ++fj) {
            float cs = 0.f;
            #pragma unroll
            for (int fi = 0; fi < 8; ++fi)
                #pragma unroll
                for (int r = 0; r < 4; ++r)
                    cs += acc[fi][fj][r];
            cs += __shfl_xor(cs, 16);
            cs += __shfl_xor(cs, 32);
            if (hk == 0)
                atomicAdd(&S[colBase + qc + fj * 16 + lr], cs);
        }
    }
}

// ---------------- final scalar reduce ----------------
__global__ __launch_bounds__(1024) void finalize_kernel(const float* __restrict__ S,
                                                        const float* __restrict__ diag,
                                                        float* __restrict__ out) {
    float s = 0.f;
    for (int i = threadIdx.x; i < N; i += 1024) s += 0.5f * __logf(S[i]);
    for (int i = threadIdx.x; i < BATCH; i += 1024) s -= __logf(diag[i]);
    #pragma unroll
    for (int m = 1; m <= 32; m <<= 1) s += __shfl_xor(s, m);
    __shared__ float sh[16];
    const int lane = threadIdx.x & 63, w = threadIdx.x >> 6;
    if (lane == 0) sh[w] = s;
    __syncthreads();
    if (threadIdx.x == 0) {
        float t = 0.f;
        #pragma unroll
        for (int i = 0; i < 16; ++i) t += sh[i];
        out[0] = t / (float)BATCH;
    }
}

extern "C" void kernel_launch(void* const* d_in, const int* in_sizes, int n_in,
                              void* d_out, int out_size, void* d_ws, size_t ws_size,
                              hipStream_t stream) {
    const float* feat = (const float*)d_in[0];
    char* ws = (char*)d_ws;
    // ws layout: fbf16 (8192*128*2 = 2MB) @0 | norms 32KB @2MB | S 32KB | diag 16KB
    unsigned short* fbf = (unsigned short*)ws;
    float* norms = (float*)(ws + (2u << 20));
    float* S     = (float*)(ws + (2u << 20) + 32768);
    float* diag  = (float*)(ws + (2u << 20) + 65536);
    float* out   = (float*)d_out;

    hipMemsetAsync(S, 0, N * sizeof(float), stream);
    prep_kernel<<<N / 4, 256, 0, stream>>>(feat, fbf, norms);
    sim_kernel<<<TRI, 512, 0, stream>>>(fbf, norms, S, diag);
    finalize_kernel<<<1, 1024, 0, stream>>>(S, diag, out);
}

// Round 3
// 90.421 us; speedup vs baseline: 1.2790x; 1.1954x over previous
//
#include <hip/hip_runtime.h>
#include <hip/hip_bf16.h>

typedef __bf16 bf16x8 __attribute__((ext_vector_type(8)));
typedef float  f32x4  __attribute__((ext_vector_type(4)));

static constexpr int D      = 128;
static constexpr int BATCH  = 4096;   // per-half batch
static constexpr int N      = 8192;   // total rows (unified Gram view)
static constexpr int BT     = 256;    // super-tile
static constexpr int NT     = N / BT; // 32
static constexpr int TRI    = NT * (NT + 1) / 2; // 528 lower-tri blocks

__device__ __forceinline__ void load_lds16(const void* g, void* l) {
    __builtin_amdgcn_global_load_lds(
        (const __attribute__((address_space(1))) unsigned int*)g,
        (__attribute__((address_space(3))) unsigned int*)l, 16, 0, 0);
}

// ---------------- prep: fp32 -> bf16 copy + row norms + zero out ----------------
__global__ __launch_bounds__(256) void prep_kernel(const float* __restrict__ f,
                                                   unsigned short* __restrict__ fb,
                                                   float* __restrict__ norms,
                                                   float* __restrict__ out) {
    if (blockIdx.x == 0 && threadIdx.x == 0) out[0] = 0.f;
    const int w = threadIdx.x >> 6, lane = threadIdx.x & 63;
    const int row = blockIdx.x * 4 + w;
    const float2 v = *(const float2*)(f + (size_t)row * D + lane * 2);
    union { __bf16 h[2]; unsigned int u; } pk;
    pk.h[0] = (__bf16)v.x; pk.h[1] = (__bf16)v.y;
    *(unsigned int*)(fb + (size_t)row * D + lane * 2) = pk.u;
    float s = v.x * v.x + v.y * v.y;
    #pragma unroll
    for (int m = 1; m <= 32; m <<= 1) s += __shfl_xor(s, m);
    if (lane == 0) norms[row] = s;
}

// ---------------- fused 256x256 Gram-tile kernel (lower triangle) ----------------
// Block (ti,tj): row-partials -> Prow[ti][tj][:], col-partials -> Prow[tj][ti][:].
// No global atomics. Stripe blocks (ti == tj+16) write sim_ab diag.
__global__ __launch_bounds__(512) void sim_kernel(const unsigned short* __restrict__ fbf,
                                                  const float* __restrict__ norms,
                                                  float* __restrict__ Prow,
                                                  float* __restrict__ diag) {
    int id = blockIdx.x;
    int ti = (int)((sqrtf(8.f * (float)id + 1.f) - 1.f) * 0.5f);
    while ((ti + 1) * (ti + 2) / 2 <= id) ++ti;
    while (ti * (ti + 1) / 2 > id) --ti;
    const int tj = id - ti * (ti + 1) / 2;
    const bool diagblk = (ti == tj);

    // LDS: two 256-row x 64-bf16 (128B/row) K-half tiles + reduce buffers.
    __shared__ __align__(16) unsigned char AsB[BT * 128];
    __shared__ __align__(16) unsigned char BsB[BT * 128];
    __shared__ float rowbuf[256];
    __shared__ float colbuf[256];

    const int tid = threadIdx.x;
    if (tid < 256) rowbuf[tid] = 0.f;
    else           colbuf[tid - 256] = 0.f;

    const int wv = tid >> 6, lane = tid & 63;
    const int lr = lane & 15, hk = lane >> 4;
    const int qr = (wv >> 2) * 128;   // wave row region (2 x 128)
    const int qc = (wv & 3) * 64;     // wave col region (4 x 64)

    const unsigned char* Abase = (const unsigned char*)fbf + (size_t)ti * BT * 256; // 256B/row
    const unsigned char* Bbase = (const unsigned char*)fbf + (size_t)tj * BT * 256;
    const unsigned char* Brd = diagblk ? AsB : BsB;

    f32x4 acc[8][4];
    #pragma unroll
    for (int i = 0; i < 8; ++i)
        #pragma unroll
        for (int j = 0; j < 4; ++j)
            acc[i][j] = (f32x4){0.f, 0.f, 0.f, 0.f};

    #pragma unroll
    for (int kp = 0; kp < 2; ++kp) {
        if (kp) __syncthreads();   // protect LDS reuse
        // Stage K-half kp: linear LDS dst (wave base + lane*16), pre-swizzled global src.
        #pragma unroll
        for (int it = 0; it < 4; ++it) {
            const int cid = it * 512 + tid;
            const int row = cid >> 3, p = cid & 7;
            const int sw = ((p ^ (row & 7)) << 4);
            load_lds16(Abase + (size_t)row * 256 + kp * 128 + sw,
                       AsB + it * 8192 + wv * 1024);
        }
        if (!diagblk) {
            #pragma unroll
            for (int it = 0; it < 4; ++it) {
                const int cid = it * 512 + tid;
                const int row = cid >> 3, p = cid & 7;
                const int sw = ((p ^ (row & 7)) << 4);
                load_lds16(Bbase + (size_t)row * 256 + kp * 128 + sw,
                           BsB + it * 8192 + wv * 1024);
            }
        }
        __syncthreads();

        #pragma unroll
        for (int l = 0; l < 2; ++l) {
            const int c = l * 4 + hk;
            bf16x8 av[8], bv[4];
            #pragma unroll
            for (int fi = 0; fi < 8; ++fi) {
                const int row = qr + fi * 16 + lr;
                av[fi] = *(const bf16x8*)(AsB + row * 128 + ((c ^ (row & 7)) << 4));
            }
            #pragma unroll
            for (int fj = 0; fj < 4; ++fj) {
                const int row = qc + fj * 16 + lr;
                bv[fj] = *(const bf16x8*)(Brd + row * 128 + ((c ^ (row & 7)) << 4));
            }
            #pragma unroll
            for (int fi = 0; fi < 8; ++fi)
                #pragma unroll
                for (int fj = 0; fj < 4; ++fj)
                    acc[fi][fj] = __builtin_amdgcn_mfma_f32_16x16x32_bf16(av[fi], bv[fj], acc[fi][fj], 0, 0, 0);
        }
    }

    // ---- epilogue: dot -> cauchy sim, diag handling, LDS reduce, direct stores ----
    float colN[4];
    #pragma unroll
    for (int fj = 0; fj < 4; ++fj)
        colN[fj] = norms[tj * BT + qc + fj * 16 + lr];

    const int colBase = tj * BT;
    const bool stripe = (ti == tj + 16);

    #pragma unroll
    for (int fi = 0; fi < 8; ++fi) {
        const int irow = qr + fi * 16 + hk * 4;  // +r
        float rowN[4];
        #pragma unroll
        for (int r = 0; r < 4; ++r)
            rowN[r] = norms[ti * BT + irow + r];
        #pragma unroll
        for (int fj = 0; fj < 4; ++fj) {
            const int icol = qc + fj * 16 + lr;
            #pragma unroll
            for (int r = 0; r < 4; ++r) {
                float sq = rowN[r] + colN[fj] - 2.f * acc[fi][fj][r];
                sq = fmaxf(sq, 0.f);
                float sim = __builtin_amdgcn_rcpf(sq + 1.f);
                if (diagblk && (irow + r == icol)) sim = 0.f;       // self-mask
                if (stripe && (irow + r == icol)) diag[colBase + icol] = sim; // ab diag
                acc[fi][fj][r] = sim;
            }
        }
    }

    // row partials: sum over fj + 16-lane (lr) tree -> LDS add (4 waves share a row)
    #pragma unroll
    for (int fi = 0; fi < 8; ++fi) {
        float rs[4];
        #pragma unroll
        for (int r = 0; r < 4; ++r)
            rs[r] = acc[fi][0][r] + acc[fi][1][r] + acc[fi][2][r] + acc[fi][3][r];
        #pragma unroll
        for (int r = 0; r < 4; ++r) {
            rs[r] += __shfl_xor(rs[r], 1);
            rs[r] += __shfl_xor(rs[r], 2);
            rs[r] += __shfl_xor(rs[r], 4);
            rs[r] += __shfl_xor(rs[r], 8);
        }
        if (lr == 0) {
            #pragma unroll
            for (int r = 0; r < 4; ++r)
                atomicAdd(&rowbuf[qr + fi * 16 + hk * 4 + r], rs[r]);
        }
    }

    // col partials (off-diag blocks): sum over fi,r + hk tree -> LDS add (2 row-halves)
    if (!diagblk) {
        #pragma unroll
        for (int fj = 0; fj < 4; ++fj) {
            float cs = 0.f;
            #pragma unroll
            for (int fi = 0; fi < 8; ++fi)
                #pragma unroll
                for (int r = 0; r < 4; ++r)
                    cs += acc[fi][fj][r];
            cs += __shfl_xor(cs, 16);
            cs += __shfl_xor(cs, 32);
            if (hk == 0)
                atomicAdd(&colbuf[qc + fj * 16 + lr], cs);
        }
    }
    __syncthreads();

    // coalesced, non-atomic global writes: each Prow slot written exactly once
    float* PR = Prow + ((size_t)ti * NT + tj) * BT;  // row side
    float* PC = Prow + ((size_t)tj * NT + ti) * BT;  // col side (transpose slot)
    if (tid < 256) {
        PR[tid] = rowbuf[tid];
        if (!diagblk) PC[tid] = colbuf[tid];
    }
}

// ---------------- finalize: reduce Prow over axis 1, logs, scalar ----------------
__global__ __launch_bounds__(256) void finalize_kernel(const float* __restrict__ Prow,
                                                       const float* __restrict__ diag,
                                                       float* __restrict__ out) {
    const int ti = blockIdx.x;          // 32 blocks, one per row-tile
    const int r  = threadIdx.x;         // 256 threads, one per row in tile
    const float* base = Prow + (size_t)ti * NT * BT + r;
    float s = 0.f;
    #pragma unroll
    for (int k = 0; k < NT; ++k) s += base[k * BT];
    const int i = ti * BT + r;
    float term = 0.5f * __logf(s);
    if (i >= BATCH) term -= __logf(diag[i - BATCH]);
    #pragma unroll
    for (int m = 1; m <= 32; m <<= 1) term += __shfl_xor(term, m);
    __shared__ float sh[4];
    if ((threadIdx.x & 63) == 0) sh[threadIdx.x >> 6] = term;
    __syncthreads();
    if (threadIdx.x == 0)
        atomicAdd(out, (sh[0] + sh[1] + sh[2] + sh[3]) / (float)BATCH);
}

extern "C" void kernel_launch(void* const* d_in, const int* in_sizes, int n_in,
                              void* d_out, int out_size, void* d_ws, size_t ws_size,
                              hipStream_t stream) {
    const float* feat = (const float*)d_in[0];
    char* ws = (char*)d_ws;
    // ws layout: fbf16 2MB @0 | norms 32KB @2MB | diag 16KB | Prow 1MB
    unsigned short* fbf = (unsigned short*)ws;
    float* norms = (float*)(ws + (2u << 20));
    float* diag  = (float*)(ws + (2u << 20) + 32768);
    float* Prow  = (float*)(ws + (2u << 20) + 49152);
    float* out   = (float*)d_out;

    prep_kernel<<<N / 4, 256, 0, stream>>>(feat, fbf, norms, out);
    sim_kernel<<<TRI, 512, 0, stream>>>(fbf, norms, Prow, diag);
    finalize_kernel<<<NT, 256, 0, stream>>>(Prow, diag, out);
}